// Round 4
// baseline (414.262 us; speedup 1.0000x reference)
//
#include <hip/hip_runtime.h>
#include <stdint.h>

#define DD 512
#define KK 4096
#define NN 32768

typedef __attribute__((ext_vector_type(8))) short bf16x8;
typedef __attribute__((ext_vector_type(4))) float f32x4;

__device__ __forceinline__ unsigned short bf16_rn(float f) {
  uint32_t u = __float_as_uint(f);
  return (unsigned short)((u + 0x7FFFu + ((u >> 16) & 1u)) >> 16);
}

// ---------------- x -> bf16 cast (8 elems/thread) ----------------
__global__ __launch_bounds__(256) void conv_x_kernel(const float4* __restrict__ x4,
                                                     unsigned short* __restrict__ xh) {
  int gid = blockIdx.x * 256 + threadIdx.x;  // NN*DD/8 threads
  float4 a = x4[gid * 2];
  float4 b = x4[gid * 2 + 1];
  union { unsigned short u[8]; uint4 q; } H;
  H.u[0] = bf16_rn(a.x); H.u[1] = bf16_rn(a.y);
  H.u[2] = bf16_rn(a.z); H.u[3] = bf16_rn(a.w);
  H.u[4] = bf16_rn(b.x); H.u[5] = bf16_rn(b.y);
  H.u[6] = bf16_rn(b.z); H.u[7] = bf16_rn(b.w);
  *(uint4*)(xh + (size_t)gid * 8) = H.q;
}

// ------- fused E prep: transpose + bf16 + he2 accumulation (+ optional fp32 Et) -------
// he2 via wave-level shfl reduce over the 32 d-lanes, then ONE atomicAdd per (k,block)
// (was: per-element atomicAdd -> 2M atomics on 4096 addresses -> 208us serialization).
template <bool WRITE_ET>
__global__ __launch_bounds__(256) void prep_et_kernel(const float* __restrict__ E,
                                                      unsigned short* __restrict__ Eth,
                                                      float* __restrict__ he2,
                                                      float* __restrict__ Et) {
  __shared__ float t[32][33];
  int bk = (blockIdx.x & 127) * 32;
  int bd = (blockIdx.x >> 7) * 32;
  int c = threadIdx.x & 31;
  int r0 = threadIdx.x >> 5;
#pragma unroll
  for (int r = r0; r < 32; r += 8) t[r][c] = E[(size_t)(bd + r) * KK + bk + c];
  __syncthreads();
#pragma unroll
  for (int i = 0; i < 4; ++i) {
    int r = r0 + i * 8;
    float v = t[c][r];  // = E[(bd+c)*KK + bk+r]  (k = bk+r, d = bd+c)
    size_t o = (size_t)(bk + r) * DD + bd + c;
    Eth[o] = bf16_rn(v);
    if (WRITE_ET) Et[o] = v;
    // reduce v^2 over c (lanes 0..31 within each wave half share a fixed r)
    float v2 = v * v;
#pragma unroll
    for (int m = 1; m < 32; m <<= 1) v2 += __shfl_xor(v2, m, 64);
    if (c == 0) atomicAdd(&he2[bk + r], 0.5f * v2);
  }
}

// ---------------- MFMA scores + argmax (single bf16 product) ----------------
// grid: (NN/128)*8 remapped XCD-aware; block = 128 tokens x 512 codes (4 nt tiles).
// LDS: double-buffered A,B tiles [128][64] bf16 (rows = 128 B), XOR-swizzled chunks:
//   LDS slot (row, pos) holds global 16B-chunk (pos ^ (row&7)).
// Schedule (T4 counted-vmcnt): per K-step,
//   stage(t+1) -> s_waitcnt vmcnt(8) [waits only stage(t)] -> s_barrier ->
//   ds_read+MFMA(t) -> s_barrier.
// The wait is BEFORE the barrier so every wave's share of tile t is in LDS when
// any wave proceeds; stage(t+1)'s 8 loads stay in flight across both barriers.
// he2 preloaded to registers (16 floats, static-indexed) so no vmem op in the loop
// forces a compiler vmcnt(0).
#define ANB 512
#define BN 128

__device__ __forceinline__ void stage_tile(const unsigned short* __restrict__ xh,
                                           const unsigned short* __restrict__ Eth,
                                           char* Ah, char* Bh, int block_m, int ncode,
                                           int dt, int w, int srow, int schunk) {
#pragma unroll
  for (int r = 0; r < 4; ++r) {
    const int rowbase = w * 32 + r * 8;
    const int arow = block_m + rowbase + srow;
    const int brow = ncode + rowbase + srow;
    const int col = dt + schunk * 8;
    __builtin_amdgcn_global_load_lds(
        (const __attribute__((address_space(1))) void*)(xh + (size_t)arow * DD + col),
        (__attribute__((address_space(3))) void*)(Ah + rowbase * 128), 16, 0, 0);
    __builtin_amdgcn_global_load_lds(
        (const __attribute__((address_space(1))) void*)(Eth + (size_t)brow * DD + col),
        (__attribute__((address_space(3))) void*)(Bh + rowbase * 128), 16, 0, 0);
  }
}

__global__ __launch_bounds__(256, 2) void argmax_mfma_kernel(
    const unsigned short* __restrict__ xh, const unsigned short* __restrict__ Eth,
    const float* __restrict__ he2, unsigned long long* __restrict__ best64) {
  __shared__ __align__(16) char smem[65536];  // 2 x {A[128][64], B[128][64]} bf16

  const int tid = threadIdx.x;
  const int w = tid >> 6;
  const int lane = tid & 63;
  const int wm = w >> 1, wk = w & 1;
  const int l15 = lane & 15, quad = lane >> 4;

  // XCD-aware bijective swizzle: 2048 wgs, 8 XCDs (wg -> XCD = blockIdx%8).
  const int orig = blockIdx.x;
  const int wgid = (orig & 7) * 256 + (orig >> 3);
  const int block_m = (wgid >> 3) * BN;
  const int nbase = (wgid & 7) * ANB;

  const int srow = lane >> 3;                       // 0..7 row within 8-row group
  const int schunk = (lane & 7) ^ (lane >> 3);      // swizzled source chunk
  const int rx = l15 & 7;                           // frag-read xor key

  // preload he2 for all 4 nt tiles x 4 tj (static-indexed -> stays in VGPRs)
  float hv[16];
#pragma unroll
  for (int nt = 0; nt < 4; ++nt)
#pragma unroll
    for (int tj = 0; tj < 4; ++tj)
      hv[nt * 4 + tj] = he2[nbase + nt * BN + wk * 64 + l15 + tj * 16];

  float best[16];
  int bidx[16];
#pragma unroll
  for (int s = 0; s < 16; ++s) { best[s] = -INFINITY; bidx[s] = 0; }

  // prologue: stage (nt=0, dt=0) into buf 0
  stage_tile(xh, Eth, smem, smem + 16384, block_m, nbase, 0, w, srow, schunk);

#pragma unroll
  for (int nt = 0; nt < 4; ++nt) {
    const int ncode = nbase + nt * BN;
    f32x4 acc[4][4];
#pragma unroll
    for (int ti = 0; ti < 4; ++ti)
#pragma unroll
      for (int tj = 0; tj < 4; ++tj) acc[ti][tj] = (f32x4){0.f, 0.f, 0.f, 0.f};

    for (int dtI = 0; dtI < 8; ++dtI) {
      // cur parity: t = nt*8+dtI, nt*8 even -> cur = dtI&1
      char* curbuf = smem + (size_t)((dtI & 1) * 32768);
      char* nxtbuf = smem + (size_t)(((dtI + 1) & 1) * 32768);

      // issue next tile's loads early (into the other buffer), then counted wait
      if (dtI < 7) {
        stage_tile(xh, Eth, nxtbuf, nxtbuf + 16384, block_m, ncode, (dtI + 1) * 64, w,
                   srow, schunk);
        asm volatile("s_waitcnt vmcnt(8)" ::: "memory");
      } else if (nt < 3) {
        stage_tile(xh, Eth, nxtbuf, nxtbuf + 16384, block_m, ncode + BN, 0, w, srow,
                   schunk);
        asm volatile("s_waitcnt vmcnt(8)" ::: "memory");
      } else {
        asm volatile("s_waitcnt vmcnt(0)" ::: "memory");
      }
      __builtin_amdgcn_s_barrier();  // all waves' stage(t) retired -> curbuf valid
      asm volatile("" ::: "memory");

      // compute current buffer
      char* Ah = curbuf;
      char* Bh = curbuf + 16384;
#pragma unroll
      for (int s = 0; s < 2; ++s) {
        const int ch = ((s * 4 + quad) ^ rx) * 16;
        bf16x8 af[4], bfv[4];
#pragma unroll
        for (int t = 0; t < 4; ++t) {
          af[t] = *(const bf16x8*)(Ah + (wm * 64 + t * 16 + l15) * 128 + ch);
          bfv[t] = *(const bf16x8*)(Bh + (wk * 64 + t * 16 + l15) * 128 + ch);
        }
#pragma unroll
        for (int ti = 0; ti < 4; ++ti)
#pragma unroll
          for (int tj = 0; tj < 4; ++tj)
            acc[ti][tj] = __builtin_amdgcn_mfma_f32_16x16x32_bf16(af[ti], bfv[tj],
                                                                  acc[ti][tj], 0, 0, 0);
      }
      asm volatile("" ::: "memory");
      __builtin_amdgcn_s_barrier();  // WAR: curbuf free for stage(t+2)
    }

    // fold this 128-code tile: score = dot - 0.5|e|^2 (he2 from registers)
    const int colb = ncode + wk * 64 + l15;
#pragma unroll
    for (int tj = 0; tj < 4; ++tj) {
      float h = hv[nt * 4 + tj];
#pragma unroll
      for (int ti = 0; ti < 4; ++ti)
#pragma unroll
        for (int r = 0; r < 4; ++r) {
          float sc = acc[ti][tj][r] - h;
          int slot = ti * 4 + r;
          if (sc > best[slot]) { best[slot] = sc; bidx[slot] = colb + tj * 16; }
        }
    }
  }

  // reduce over the 16 col-lanes per row group, then cross-block atomicMax
#pragma unroll
  for (int slot = 0; slot < 16; ++slot) {
    float v = best[slot];
    int ii = bidx[slot];
#pragma unroll
    for (int m = 1; m < 16; m <<= 1) {
      float ov = __shfl_xor(v, m, 64);
      int oi = __shfl_xor(ii, m, 64);
      if (ov > v || (ov == v && oi < ii)) { v = ov; ii = oi; }
    }
    if (l15 == 0) {
      int row = block_m + wm * 64 + (slot >> 2) * 16 + quad * 4 + (slot & 3);
      uint32_t b = __float_as_uint(v);
      uint32_t mm = (b & 0x80000000u) ? ~b : (b | 0x80000000u);
      unsigned long long packed = ((unsigned long long)mm << 32) | (uint32_t)(~(uint32_t)ii);
      atomicMax(&best64[row], packed);
    }
  }
}

// ---------------- fallback fp32 argmax (used when ws too small) ----------------
#define BM 128
#define BK 128
#define KS 4
#define KPB (KK / KS)
#define BD 32

__global__ __launch_bounds__(256, 4) void argmax_kernel(
    const float* __restrict__ x, const float* __restrict__ E,
    const float* __restrict__ he2, unsigned long long* __restrict__ best64) {
  __shared__ __align__(16) char smem[33280];
  float (*xs)[132] = (float (*)[132])smem;
  float (*es)[BK] = (float (*)[BK])(smem + 16896);

  const int tid = threadIdx.x;
  const int wave = tid >> 6;
  const int lane = tid & 63;
  const int wm = wave >> 1, wk = wave & 1;
  const int tm = lane >> 3, tk = lane & 7;
  const int block_m = (blockIdx.x >> 2) * BM;
  const int kbase = (blockIdx.x & 3) * KPB;

  float best[8];
  int bidx[8];
#pragma unroll
  for (int i = 0; i < 8; ++i) { best[i] = -INFINITY; bidx[i] = 0; }

  const int xtok = tid >> 3;
  const int xd4 = tid & 7;
  const int erow_lane = (lane >> 5);
  const int ecol = (lane & 31) * 4;

  for (int kt = 0; kt < KPB; kt += BK) {
    const int k0 = kbase + kt;
    float acc[8][8];
#pragma unroll
    for (int i = 0; i < 8; ++i)
#pragma unroll
      for (int j = 0; j < 8; ++j) acc[i][j] = 0.f;

    for (int dt = 0; dt < DD; dt += BD) {
      __syncthreads();
#pragma unroll
      for (int r = 0; r < 4; ++r) {
        int row = r * 8 + wave * 2;
        const float* gp = E + (size_t)(dt + row + erow_lane) * KK + k0 + ecol;
        __builtin_amdgcn_global_load_lds(
            (const __attribute__((address_space(1))) void*)gp,
            (__attribute__((address_space(3))) void*)&es[row][0], 16, 0, 0);
      }
#pragma unroll
      for (int r = 0; r < 4; ++r) {
        int tok = xtok + r * 32;
        float4 v = *(const float4*)(x + (size_t)(block_m + tok) * DD + dt + xd4 * 4);
        xs[xd4 * 4 + 0][tok] = v.x;
        xs[xd4 * 4 + 1][tok] = v.y;
        xs[xd4 * 4 + 2][tok] = v.z;
        xs[xd4 * 4 + 3][tok] = v.w;
      }
      __syncthreads();
#pragma unroll 4
      for (int d = 0; d < BD; ++d) {
        const float4 a0 = *(const float4*)&xs[d][wm * 64 + tm * 8];
        const float4 a1 = *(const float4*)&xs[d][wm * 64 + tm * 8 + 4];
        const float4 b0 = *(const float4*)&es[d][wk * 64 + tk * 8];
        const float4 b1 = *(const float4*)&es[d][wk * 64 + tk * 8 + 4];
        const float av[8] = {a0.x, a0.y, a0.z, a0.w, a1.x, a1.y, a1.z, a1.w};
        const float bv[8] = {b0.x, b0.y, b0.z, b0.w, b1.x, b1.y, b1.z, b1.w};
#pragma unroll
        for (int i = 0; i < 8; ++i)
#pragma unroll
          for (int j = 0; j < 8; ++j) acc[i][j] = fmaf(av[i], bv[j], acc[i][j]);
      }
    }
    const int kcol = k0 + wk * 64 + tk * 8;
    float4 h0 = *(const float4*)(he2 + kcol);
    float4 h1 = *(const float4*)(he2 + kcol + 4);
    const float hv[8] = {h0.x, h0.y, h0.z, h0.w, h1.x, h1.y, h1.z, h1.w};
#pragma unroll
    for (int i = 0; i < 8; ++i) {
#pragma unroll
      for (int j = 0; j < 8; ++j) {
        float s = acc[i][j] - hv[j];
        if (s > best[i]) { best[i] = s; bidx[i] = kcol + j; }
      }
    }
  }

  __syncthreads();
  float (*rv)[17] = (float (*)[17])smem;
  int (*ri)[17] = (int (*)[17])(smem + 8704);
#pragma unroll
  for (int i = 0; i < 8; ++i) {
    int tok = wm * 64 + tm * 8 + i;
    rv[tok][wk * 8 + tk] = best[i];
    ri[tok][wk * 8 + tk] = bidx[i];
  }
  __syncthreads();
  if (tid < BM) {
    float bv = rv[tid][0];
    int bi = ri[tid][0];
#pragma unroll
    for (int t = 1; t < 16; ++t) {
      float v = rv[tid][t];
      int ii = ri[tid][t];
      if (v > bv || (v == bv && ii < bi)) { bv = v; bi = ii; }
    }
    uint32_t b = __float_as_uint(bv);
    uint32_t m = (b & 0x80000000u) ? ~b : (b | 0x80000000u);
    unsigned long long packed = ((unsigned long long)m << 32) | (uint32_t)(~(uint32_t)bi);
    atomicMax(&best64[block_m + tid], packed);
  }
}

// ---------------- gather quantized + sum((q-x)^2) + counts ----------------
__global__ __launch_bounds__(256) void gather_et_kernel(
    const float* __restrict__ x, const float* __restrict__ Et,
    const unsigned long long* __restrict__ best64, float* __restrict__ out,
    float* __restrict__ partials, int* __restrict__ counts) {
  __shared__ float sh[256];
  int tid = threadIdx.x;
  int gid = blockIdx.x * 256 + tid;
  int n = gid >> 7;
  int d4 = gid & 127;
  int k = (int)(~(uint32_t)best64[n]);
  float4 q = *(const float4*)(Et + (size_t)k * DD + d4 * 4);
  float4 xv = *(const float4*)(x + (size_t)n * DD + d4 * 4);
  *(float4*)(out + (size_t)n * DD + d4 * 4) = q;
  float dx0 = q.x - xv.x, dx1 = q.y - xv.y, dx2 = q.z - xv.z, dx3 = q.w - xv.w;
  sh[tid] = dx0 * dx0 + dx1 * dx1 + dx2 * dx2 + dx3 * dx3;
  if (d4 == 0) atomicAdd(&counts[k], 1);
  __syncthreads();
  for (int s = 128; s > 0; s >>= 1) {
    if (tid < s) sh[tid] += sh[tid + s];
    __syncthreads();
  }
  if (tid == 0) atomicAdd(&partials[blockIdx.x & 255], sh[0]);
}

__global__ __launch_bounds__(256) void gather_direct_kernel(
    const float* __restrict__ x, const float* __restrict__ E,
    const unsigned long long* __restrict__ best64, float* __restrict__ out,
    float* __restrict__ partials, int* __restrict__ counts) {
  __shared__ float sh[256];
  int tid = threadIdx.x;
  int gid = blockIdx.x * 256 + tid;
  int n = gid >> 7;
  int d4 = gid & 127;
  int k = (int)(~(uint32_t)best64[n]);
  float4 q;
  q.x = E[(size_t)(d4 * 4 + 0) * KK + k];
  q.y = E[(size_t)(d4 * 4 + 1) * KK + k];
  q.z = E[(size_t)(d4 * 4 + 2) * KK + k];
  q.w = E[(size_t)(d4 * 4 + 3) * KK + k];
  float4 xv = *(const float4*)(x + (size_t)n * DD + d4 * 4);
  *(float4*)(out + (size_t)n * DD + d4 * 4) = q;
  float dx0 = q.x - xv.x, dx1 = q.y - xv.y, dx2 = q.z - xv.z, dx3 = q.w - xv.w;
  sh[tid] = dx0 * dx0 + dx1 * dx1 + dx2 * dx2 + dx3 * dx3;
  if (d4 == 0) atomicAdd(&counts[k], 1);
  __syncthreads();
  for (int s = 128; s > 0; s >>= 1) {
    if (tid < s) sh[tid] += sh[tid + s];
    __syncthreads();
  }
  if (tid == 0) atomicAdd(&partials[blockIdx.x & 255], sh[0]);
}

// ---------------- loss + perplexity ----------------
__global__ __launch_bounds__(256) void finalize_kernel(
    const int* __restrict__ counts, const float* __restrict__ partials,
    float* __restrict__ out) {
  __shared__ float sh[256];
  int tid = threadIdx.x;
  float h = 0.f;
  for (int k = tid; k < KK; k += 256) {
    float p = (float)counts[k] * (1.0f / (float)NN);
    h += p * logf(p + 1e-10f);
  }
  sh[tid] = h;
  __syncthreads();
  for (int s = 128; s > 0; s >>= 1) {
    if (tid < s) sh[tid] += sh[tid + s];
    __syncthreads();
  }
  float H = sh[0];
  __syncthreads();
  sh[tid] = partials[tid];
  __syncthreads();
  for (int s = 128; s > 0; s >>= 1) {
    if (tid < s) sh[tid] += sh[tid + s];
    __syncthreads();
  }
  if (tid == 0) {
    float mse = sh[0] / (float)((size_t)NN * DD);
    out[(size_t)NN * DD] = 1.25f * mse;
    out[(size_t)NN * DD + 1] = expf(-H);
  }
}

extern "C" void kernel_launch(void* const* d_in, const int* in_sizes, int n_in,
                              void* d_out, int out_size, void* d_ws, size_t ws_size,
                              hipStream_t stream) {
  const float* x = (const float*)d_in[0];
  const float* E = (const float*)d_in[1];
  float* out = (float*)d_out;
  char* ws = (char*)d_ws;

  // common ws layout
  unsigned long long* best64 = (unsigned long long*)(ws + 0);  // 262144
  float* he2 = (float*)(ws + 262144);                          // 16384
  int* counts = (int*)(ws + 278528);                           // 16384
  float* partials = (float*)(ws + 294912);                     // 1024
  // MFMA path extras
  unsigned short* Eth = (unsigned short*)(ws + 295936);        // 4 MiB
  float* Et = (float*)(ws + 4490240);                          // 8 MiB (optional)
  const size_t NEED_MFMA = 4490240;
  const size_t NEED_ET = 4490240 + (size_t)DD * KK * 4;

  // zero best64 + he2 (atomically accumulated) + counts + partials
  hipMemsetAsync(ws, 0, 295936, stream);

  if (ws_size >= NEED_MFMA) {
    unsigned short* xh = (unsigned short*)d_out;  // overwritten by gather later
    const bool use_et = ws_size >= NEED_ET;

    conv_x_kernel<<<(NN * DD / 8) / 256, 256, 0, stream>>>((const float4*)x, xh);
    if (use_et)
      prep_et_kernel<true><<<(KK / 32) * (DD / 32), 256, 0, stream>>>(E, Eth, he2, Et);
    else
      prep_et_kernel<false><<<(KK / 32) * (DD / 32), 256, 0, stream>>>(E, Eth, he2, Et);
    argmax_mfma_kernel<<<(NN / 128) * 8, 256, 0, stream>>>(xh, Eth, he2, best64);
    if (use_et)
      gather_et_kernel<<<(NN * (DD / 4)) / 256, 256, 0, stream>>>(x, Et, best64, out,
                                                                  partials, counts);
    else
      gather_direct_kernel<<<(NN * (DD / 4)) / 256, 256, 0, stream>>>(x, E, best64, out,
                                                                      partials, counts);
  } else {
    // fp32 fallback: needs exact he2 first (no Eth write available? reuse prep path)
    prep_et_kernel<false><<<(KK / 32) * (DD / 32), 256, 0, stream>>>(
        E, (unsigned short*)(ws + 295936), he2, (float*)nullptr);
    argmax_kernel<<<(NN / BM) * KS, 256, 0, stream>>>(x, E, he2, best64);
    gather_direct_kernel<<<(NN * (DD / 4)) / 256, 256, 0, stream>>>(x, E, best64, out,
                                                                    partials, counts);
  }
  finalize_kernel<<<1, 256, 0, stream>>>(counts, partials, out);
}

// Round 5
// 315.838 us; speedup vs baseline: 1.3116x; 1.3116x over previous
//
#include <hip/hip_runtime.h>
#include <stdint.h>

#define DD 512
#define KK 4096
#define NN 32768

typedef __attribute__((ext_vector_type(8))) short bf16x8;
typedef __attribute__((ext_vector_type(4))) float f32x4;

__device__ __forceinline__ unsigned short bf16_rn(float f) {
  uint32_t u = __float_as_uint(f);
  return (unsigned short)((u + 0x7FFFu + ((u >> 16) & 1u)) >> 16);
}

// ---------------- x -> bf16 cast (8 elems/thread) ----------------
__global__ __launch_bounds__(256) void conv_x_kernel(const float4* __restrict__ x4,
                                                     unsigned short* __restrict__ xh) {
  int gid = blockIdx.x * 256 + threadIdx.x;  // NN*DD/8 threads
  float4 a = x4[gid * 2];
  float4 b = x4[gid * 2 + 1];
  union { unsigned short u[8]; uint4 q; } H;
  H.u[0] = bf16_rn(a.x); H.u[1] = bf16_rn(a.y);
  H.u[2] = bf16_rn(a.z); H.u[3] = bf16_rn(a.w);
  H.u[4] = bf16_rn(b.x); H.u[5] = bf16_rn(b.y);
  H.u[6] = bf16_rn(b.z); H.u[7] = bf16_rn(b.w);
  *(uint4*)(xh + (size_t)gid * 8) = H.q;
}

// ------- fused E prep: transpose + bf16 + he2 accumulation (+ optional fp32 Et) -------
// he2 via wave-level shfl reduce over the 32 d-lanes, then ONE atomicAdd per (k,block)
// (was: per-element atomicAdd -> 2M atomics on 4096 addresses -> 208us serialization).
template <bool WRITE_ET>
__global__ __launch_bounds__(256) void prep_et_kernel(const float* __restrict__ E,
                                                      unsigned short* __restrict__ Eth,
                                                      float* __restrict__ he2,
                                                      float* __restrict__ Et) {
  __shared__ float t[32][33];
  int bk = (blockIdx.x & 127) * 32;
  int bd = (blockIdx.x >> 7) * 32;
  int c = threadIdx.x & 31;
  int r0 = threadIdx.x >> 5;
#pragma unroll
  for (int r = r0; r < 32; r += 8) t[r][c] = E[(size_t)(bd + r) * KK + bk + c];
  __syncthreads();
#pragma unroll
  for (int i = 0; i < 4; ++i) {
    int r = r0 + i * 8;
    float v = t[c][r];  // = E[(bd+c)*KK + bk+r]  (k = bk+r, d = bd+c)
    size_t o = (size_t)(bk + r) * DD + bd + c;
    Eth[o] = bf16_rn(v);
    if (WRITE_ET) Et[o] = v;
    // reduce v^2 over c (lanes 0..31 within each wave half share a fixed r)
    float v2 = v * v;
#pragma unroll
    for (int m = 1; m < 32; m <<= 1) v2 += __shfl_xor(v2, m, 64);
    if (c == 0) atomicAdd(&he2[bk + r], 0.5f * v2);
  }
}

// ---------------- MFMA scores + argmax (single bf16 product) ----------------
// grid: (NN/128)*8 remapped XCD-aware; block = 128 tokens x 512 codes (4 nt tiles).
// LDS: double-buffered A,B tiles [128][64] bf16 (rows = 128 B), XOR-swizzled chunks:
//   LDS slot (row, pos) holds global 16B-chunk (pos ^ (row&7)).
// Schedule (T4 counted-vmcnt, MINIMAL — R4's nt-unroll + hv preload reverted, they
// caused scratch spill/fill = 284 MB WRITE_SIZE):
//   stage(t+1) -> s_waitcnt vmcnt(8) [waits only stage(t); stage(t+1) in flight]
//   -> s_barrier [curbuf valid for all waves] -> ds_read+MFMA(t)
//   -> s_barrier [WAR: curbuf may be overwritten by stage(t+2)].
#define ANB 512
#define BN 128

__device__ __forceinline__ void stage_tile(const unsigned short* __restrict__ xh,
                                           const unsigned short* __restrict__ Eth,
                                           char* Ah, char* Bh, int block_m, int ncode,
                                           int dt, int w, int srow, int schunk) {
#pragma unroll
  for (int r = 0; r < 4; ++r) {
    const int rowbase = w * 32 + r * 8;
    const int arow = block_m + rowbase + srow;
    const int brow = ncode + rowbase + srow;
    const int col = dt + schunk * 8;
    __builtin_amdgcn_global_load_lds(
        (const __attribute__((address_space(1))) void*)(xh + (size_t)arow * DD + col),
        (__attribute__((address_space(3))) void*)(Ah + rowbase * 128), 16, 0, 0);
    __builtin_amdgcn_global_load_lds(
        (const __attribute__((address_space(1))) void*)(Eth + (size_t)brow * DD + col),
        (__attribute__((address_space(3))) void*)(Bh + rowbase * 128), 16, 0, 0);
  }
}

__global__ __launch_bounds__(256, 2) void argmax_mfma_kernel(
    const unsigned short* __restrict__ xh, const unsigned short* __restrict__ Eth,
    const float* __restrict__ he2, unsigned long long* __restrict__ best64) {
  __shared__ __align__(16) char smem[65536];  // 2 x {A[128][64], B[128][64]} bf16

  const int tid = threadIdx.x;
  const int w = tid >> 6;
  const int lane = tid & 63;
  const int wm = w >> 1, wk = w & 1;
  const int l15 = lane & 15, quad = lane >> 4;

  // XCD-aware bijective swizzle: 2048 wgs, 8 XCDs (wg -> XCD = blockIdx%8).
  const int orig = blockIdx.x;
  const int wgid = (orig & 7) * 256 + (orig >> 3);
  const int block_m = (wgid >> 3) * BN;
  const int nbase = (wgid & 7) * ANB;

  const int srow = lane >> 3;                       // 0..7 row within 8-row group
  const int schunk = (lane & 7) ^ (lane >> 3);      // swizzled source chunk
  const int rx = l15 & 7;                           // frag-read xor key

  float best[16];
  int bidx[16];
#pragma unroll
  for (int s = 0; s < 16; ++s) { best[s] = -INFINITY; bidx[s] = 0; }

  // prologue: stage (nt=0, dt=0) into buf 0 (first loop iter's wait+barrier covers it)
  stage_tile(xh, Eth, smem, smem + 16384, block_m, nbase, 0, w, srow, schunk);
  int cur = 0;

  for (int nt = 0; nt < 4; ++nt) {
    const int ncode = nbase + nt * BN;
    f32x4 acc[4][4];
#pragma unroll
    for (int ti = 0; ti < 4; ++ti)
#pragma unroll
      for (int tj = 0; tj < 4; ++tj) acc[ti][tj] = (f32x4){0.f, 0.f, 0.f, 0.f};

    for (int dtI = 0; dtI < 8; ++dtI) {
      char* curbuf = smem + cur * 32768;
      char* nxtbuf = smem + (cur ^ 1) * 32768;

      // issue next tile's loads early (into the other buffer), counted wait on cur
      if (dtI < 7) {
        stage_tile(xh, Eth, nxtbuf, nxtbuf + 16384, block_m, ncode, (dtI + 1) * 64, w,
                   srow, schunk);
        asm volatile("s_waitcnt vmcnt(8)" ::: "memory");
      } else if (nt < 3) {
        stage_tile(xh, Eth, nxtbuf, nxtbuf + 16384, block_m, ncode + BN, 0, w, srow,
                   schunk);
        asm volatile("s_waitcnt vmcnt(8)" ::: "memory");
      } else {
        asm volatile("s_waitcnt vmcnt(0)" ::: "memory");
      }
      __builtin_amdgcn_s_barrier();  // all waves' stage(t) retired -> curbuf valid
      asm volatile("" ::: "memory");

      // compute current buffer
      char* Ah = curbuf;
      char* Bh = curbuf + 16384;
#pragma unroll
      for (int s = 0; s < 2; ++s) {
        const int ch = ((s * 4 + quad) ^ rx) * 16;
        bf16x8 af[4], bfv[4];
#pragma unroll
        for (int t = 0; t < 4; ++t) {
          af[t] = *(const bf16x8*)(Ah + (wm * 64 + t * 16 + l15) * 128 + ch);
          bfv[t] = *(const bf16x8*)(Bh + (wk * 64 + t * 16 + l15) * 128 + ch);
        }
#pragma unroll
        for (int ti = 0; ti < 4; ++ti)
#pragma unroll
          for (int tj = 0; tj < 4; ++tj)
            acc[ti][tj] = __builtin_amdgcn_mfma_f32_16x16x32_bf16(af[ti], bfv[tj],
                                                                  acc[ti][tj], 0, 0, 0);
      }
      asm volatile("" ::: "memory");
      __builtin_amdgcn_s_barrier();  // WAR: curbuf free for stage(t+2)
      cur ^= 1;
    }

    // fold this 128-code tile: score = dot - 0.5|e|^2
    // (he2 load drains the in-flight prefetch once per nt tile — lands under the
    //  fold's VALU work, acceptable; keeping it here avoids R4's hv-scratch spill)
    const int colb = ncode + wk * 64 + l15;
#pragma unroll
    for (int tj = 0; tj < 4; ++tj) {
      float h = he2[colb + tj * 16];
#pragma unroll
      for (int ti = 0; ti < 4; ++ti)
#pragma unroll
        for (int r = 0; r < 4; ++r) {
          float sc = acc[ti][tj][r] - h;
          int slot = ti * 4 + r;
          if (sc > best[slot]) { best[slot] = sc; bidx[slot] = colb + tj * 16; }
        }
    }
  }

  // reduce over the 16 col-lanes per row group, then cross-block atomicMax
#pragma unroll
  for (int slot = 0; slot < 16; ++slot) {
    float v = best[slot];
    int ii = bidx[slot];
#pragma unroll
    for (int m = 1; m < 16; m <<= 1) {
      float ov = __shfl_xor(v, m, 64);
      int oi = __shfl_xor(ii, m, 64);
      if (ov > v || (ov == v && oi < ii)) { v = ov; ii = oi; }
    }
    if (l15 == 0) {
      int row = block_m + wm * 64 + (slot >> 2) * 16 + quad * 4 + (slot & 3);
      uint32_t b = __float_as_uint(v);
      uint32_t mm = (b & 0x80000000u) ? ~b : (b | 0x80000000u);
      unsigned long long packed = ((unsigned long long)mm << 32) | (uint32_t)(~(uint32_t)ii);
      atomicMax(&best64[row], packed);
    }
  }
}

// ---------------- fallback fp32 argmax (used when ws too small) ----------------
#define BM 128
#define BK 128
#define KS 4
#define KPB (KK / KS)
#define BD 32

__global__ __launch_bounds__(256, 4) void argmax_kernel(
    const float* __restrict__ x, const float* __restrict__ E,
    const float* __restrict__ he2, unsigned long long* __restrict__ best64) {
  __shared__ __align__(16) char smem[33280];
  float (*xs)[132] = (float (*)[132])smem;
  float (*es)[BK] = (float (*)[BK])(smem + 16896);

  const int tid = threadIdx.x;
  const int wave = tid >> 6;
  const int lane = tid & 63;
  const int wm = wave >> 1, wk = wave & 1;
  const int tm = lane >> 3, tk = lane & 7;
  const int block_m = (blockIdx.x >> 2) * BM;
  const int kbase = (blockIdx.x & 3) * KPB;

  float best[8];
  int bidx[8];
#pragma unroll
  for (int i = 0; i < 8; ++i) { best[i] = -INFINITY; bidx[i] = 0; }

  const int xtok = tid >> 3;
  const int xd4 = tid & 7;
  const int erow_lane = (lane >> 5);
  const int ecol = (lane & 31) * 4;

  for (int kt = 0; kt < KPB; kt += BK) {
    const int k0 = kbase + kt;
    float acc[8][8];
#pragma unroll
    for (int i = 0; i < 8; ++i)
#pragma unroll
      for (int j = 0; j < 8; ++j) acc[i][j] = 0.f;

    for (int dt = 0; dt < DD; dt += BD) {
      __syncthreads();
#pragma unroll
      for (int r = 0; r < 4; ++r) {
        int row = r * 8 + wave * 2;
        const float* gp = E + (size_t)(dt + row + erow_lane) * KK + k0 + ecol;
        __builtin_amdgcn_global_load_lds(
            (const __attribute__((address_space(1))) void*)gp,
            (__attribute__((address_space(3))) void*)&es[row][0], 16, 0, 0);
      }
#pragma unroll
      for (int r = 0; r < 4; ++r) {
        int tok = xtok + r * 32;
        float4 v = *(const float4*)(x + (size_t)(block_m + tok) * DD + dt + xd4 * 4);
        xs[xd4 * 4 + 0][tok] = v.x;
        xs[xd4 * 4 + 1][tok] = v.y;
        xs[xd4 * 4 + 2][tok] = v.z;
        xs[xd4 * 4 + 3][tok] = v.w;
      }
      __syncthreads();
#pragma unroll 4
      for (int d = 0; d < BD; ++d) {
        const float4 a0 = *(const float4*)&xs[d][wm * 64 + tm * 8];
        const float4 a1 = *(const float4*)&xs[d][wm * 64 + tm * 8 + 4];
        const float4 b0 = *(const float4*)&es[d][wk * 64 + tk * 8];
        const float4 b1 = *(const float4*)&es[d][wk * 64 + tk * 8 + 4];
        const float av[8] = {a0.x, a0.y, a0.z, a0.w, a1.x, a1.y, a1.z, a1.w};
        const float bv[8] = {b0.x, b0.y, b0.z, b0.w, b1.x, b1.y, b1.z, b1.w};
#pragma unroll
        for (int i = 0; i < 8; ++i)
#pragma unroll
          for (int j = 0; j < 8; ++j) acc[i][j] = fmaf(av[i], bv[j], acc[i][j]);
      }
    }
    const int kcol = k0 + wk * 64 + tk * 8;
    float4 h0 = *(const float4*)(he2 + kcol);
    float4 h1 = *(const float4*)(he2 + kcol + 4);
    const float hv[8] = {h0.x, h0.y, h0.z, h0.w, h1.x, h1.y, h1.z, h1.w};
#pragma unroll
    for (int i = 0; i < 8; ++i) {
#pragma unroll
      for (int j = 0; j < 8; ++j) {
        float s = acc[i][j] - hv[j];
        if (s > best[i]) { best[i] = s; bidx[i] = kcol + j; }
      }
    }
  }

  __syncthreads();
  float (*rv)[17] = (float (*)[17])smem;
  int (*ri)[17] = (int (*)[17])(smem + 8704);
#pragma unroll
  for (int i = 0; i < 8; ++i) {
    int tok = wm * 64 + tm * 8 + i;
    rv[tok][wk * 8 + tk] = best[i];
    ri[tok][wk * 8 + tk] = bidx[i];
  }
  __syncthreads();
  if (tid < BM) {
    float bv = rv[tid][0];
    int bi = ri[tid][0];
#pragma unroll
    for (int t = 1; t < 16; ++t) {
      float v = rv[tid][t];
      int ii = ri[tid][t];
      if (v > bv || (v == bv && ii < bi)) { bv = v; bi = ii; }
    }
    uint32_t b = __float_as_uint(bv);
    uint32_t m = (b & 0x80000000u) ? ~b : (b | 0x80000000u);
    unsigned long long packed = ((unsigned long long)m << 32) | (uint32_t)(~(uint32_t)bi);
    atomicMax(&best64[block_m + tid], packed);
  }
}

// ---------------- gather quantized + sum((q-x)^2) + counts ----------------
__global__ __launch_bounds__(256) void gather_et_kernel(
    const float* __restrict__ x, const float* __restrict__ Et,
    const unsigned long long* __restrict__ best64, float* __restrict__ out,
    float* __restrict__ partials, int* __restrict__ counts) {
  __shared__ float sh[256];
  int tid = threadIdx.x;
  int gid = blockIdx.x * 256 + tid;
  int n = gid >> 7;
  int d4 = gid & 127;
  int k = (int)(~(uint32_t)best64[n]);
  float4 q = *(const float4*)(Et + (size_t)k * DD + d4 * 4);
  float4 xv = *(const float4*)(x + (size_t)n * DD + d4 * 4);
  *(float4*)(out + (size_t)n * DD + d4 * 4) = q;
  float dx0 = q.x - xv.x, dx1 = q.y - xv.y, dx2 = q.z - xv.z, dx3 = q.w - xv.w;
  sh[tid] = dx0 * dx0 + dx1 * dx1 + dx2 * dx2 + dx3 * dx3;
  if (d4 == 0) atomicAdd(&counts[k], 1);
  __syncthreads();
  for (int s = 128; s > 0; s >>= 1) {
    if (tid < s) sh[tid] += sh[tid + s];
    __syncthreads();
  }
  if (tid == 0) atomicAdd(&partials[blockIdx.x & 255], sh[0]);
}

__global__ __launch_bounds__(256) void gather_direct_kernel(
    const float* __restrict__ x, const float* __restrict__ E,
    const unsigned long long* __restrict__ best64, float* __restrict__ out,
    float* __restrict__ partials, int* __restrict__ counts) {
  __shared__ float sh[256];
  int tid = threadIdx.x;
  int gid = blockIdx.x * 256 + tid;
  int n = gid >> 7;
  int d4 = gid & 127;
  int k = (int)(~(uint32_t)best64[n]);
  float4 q;
  q.x = E[(size_t)(d4 * 4 + 0) * KK + k];
  q.y = E[(size_t)(d4 * 4 + 1) * KK + k];
  q.z = E[(size_t)(d4 * 4 + 2) * KK + k];
  q.w = E[(size_t)(d4 * 4 + 3) * KK + k];
  float4 xv = *(const float4*)(x + (size_t)n * DD + d4 * 4);
  *(float4*)(out + (size_t)n * DD + d4 * 4) = q;
  float dx0 = q.x - xv.x, dx1 = q.y - xv.y, dx2 = q.z - xv.z, dx3 = q.w - xv.w;
  sh[tid] = dx0 * dx0 + dx1 * dx1 + dx2 * dx2 + dx3 * dx3;
  if (d4 == 0) atomicAdd(&counts[k], 1);
  __syncthreads();
  for (int s = 128; s > 0; s >>= 1) {
    if (tid < s) sh[tid] += sh[tid + s];
    __syncthreads();
  }
  if (tid == 0) atomicAdd(&partials[blockIdx.x & 255], sh[0]);
}

// ---------------- loss + perplexity ----------------
__global__ __launch_bounds__(256) void finalize_kernel(
    const int* __restrict__ counts, const float* __restrict__ partials,
    float* __restrict__ out) {
  __shared__ float sh[256];
  int tid = threadIdx.x;
  float h = 0.f;
  for (int k = tid; k < KK; k += 256) {
    float p = (float)counts[k] * (1.0f / (float)NN);
    h += p * logf(p + 1e-10f);
  }
  sh[tid] = h;
  __syncthreads();
  for (int s = 128; s > 0; s >>= 1) {
    if (tid < s) sh[tid] += sh[tid + s];
    __syncthreads();
  }
  float H = sh[0];
  __syncthreads();
  sh[tid] = partials[tid];
  __syncthreads();
  for (int s = 128; s > 0; s >>= 1) {
    if (tid < s) sh[tid] += sh[tid + s];
    __syncthreads();
  }
  if (tid == 0) {
    float mse = sh[0] / (float)((size_t)NN * DD);
    out[(size_t)NN * DD] = 1.25f * mse;
    out[(size_t)NN * DD + 1] = expf(-H);
  }
}

extern "C" void kernel_launch(void* const* d_in, const int* in_sizes, int n_in,
                              void* d_out, int out_size, void* d_ws, size_t ws_size,
                              hipStream_t stream) {
  const float* x = (const float*)d_in[0];
  const float* E = (const float*)d_in[1];
  float* out = (float*)d_out;
  char* ws = (char*)d_ws;

  // common ws layout
  unsigned long long* best64 = (unsigned long long*)(ws + 0);  // 262144
  float* he2 = (float*)(ws + 262144);                          // 16384
  int* counts = (int*)(ws + 278528);                           // 16384
  float* partials = (float*)(ws + 294912);                     // 1024
  // MFMA path extras
  unsigned short* Eth = (unsigned short*)(ws + 295936);        // 4 MiB
  float* Et = (float*)(ws + 4490240);                          // 8 MiB (optional)
  const size_t NEED_MFMA = 4490240;
  const size_t NEED_ET = 4490240 + (size_t)DD * KK * 4;

  // zero best64 + he2 (atomically accumulated) + counts + partials
  hipMemsetAsync(ws, 0, 295936, stream);

  if (ws_size >= NEED_MFMA) {
    unsigned short* xh = (unsigned short*)d_out;  // overwritten by gather later
    const bool use_et = ws_size >= NEED_ET;

    conv_x_kernel<<<(NN * DD / 8) / 256, 256, 0, stream>>>((const float4*)x, xh);
    if (use_et)
      prep_et_kernel<true><<<(KK / 32) * (DD / 32), 256, 0, stream>>>(E, Eth, he2, Et);
    else
      prep_et_kernel<false><<<(KK / 32) * (DD / 32), 256, 0, stream>>>(E, Eth, he2, Et);
    argmax_mfma_kernel<<<(NN / 128) * 8, 256, 0, stream>>>(xh, Eth, he2, best64);
    if (use_et)
      gather_et_kernel<<<(NN * (DD / 4)) / 256, 256, 0, stream>>>(x, Et, best64, out,
                                                                  partials, counts);
    else
      gather_direct_kernel<<<(NN * (DD / 4)) / 256, 256, 0, stream>>>(x, E, best64, out,
                                                                      partials, counts);
  } else {
    // fp32 fallback: needs exact he2 first (no Eth write available? reuse prep path)
    prep_et_kernel<false><<<(KK / 32) * (DD / 32), 256, 0, stream>>>(
        E, (unsigned short*)(ws + 295936), he2, (float*)nullptr);
    argmax_kernel<<<(NN / BM) * KS, 256, 0, stream>>>(x, E, he2, best64);
    gather_direct_kernel<<<(NN * (DD / 4)) / 256, 256, 0, stream>>>(x, E, best64, out,
                                                                    partials, counts);
  }
  finalize_kernel<<<1, 256, 0, stream>>>(counts, partials, out);
}